// Round 2
// baseline (81.235 us; speedup 1.0000x reference)
//
#include <hip/hip_runtime.h>
#include <hip/hip_bf16.h>

// Sizes (fixed by the reference)
#define NL 3      // layers
#define NB 128    // batch
#define NO 64     // objects
#define ND 64     // emb dim
#define NQ 32     // preds per pair
#define NP 4032   // 64*63 ordered pairs

typedef __bf16 bf16x8 __attribute__((ext_vector_type(8)));
typedef float  f32x4  __attribute__((ext_vector_type(4)));

__device__ __forceinline__ float sigm(float x) {
  return __builtin_amdgcn_rcpf(1.0f + __expf(-x));
}

__device__ __forceinline__ bf16x8 pack_bf16(const f32x4 a, const f32x4 b) {
  bf16x8 r;
  r[0] = (__bf16)a[0]; r[1] = (__bf16)a[1]; r[2] = (__bf16)a[2]; r[3] = (__bf16)a[3];
  r[4] = (__bf16)b[0]; r[5] = (__bf16)b[1]; r[6] = (__bf16)b[2]; r[7] = (__bf16)b[3];
  return r;
}

// ---------------------------------------------------------------------------
// Single fused kernel. grid = 3*128*2 = 768 (blk = l*256 + b*2 + ic), 256 thr.
//
// P0: gather e rows (emb[ids]), exact f32 e-copy (l==0 blocks), mean (f32).
// P1: M_s[d] = mean.W1c[d] + b1  (f32, exact).
// P2: first layer via MFMA (bf16): UpM_s[i_loc][d] = e_i.W1a[d] + M_s[d]
//     (only this block's 32 i rows) and V_s[j][d] = e_j.W1b[d] (all 64 j).
// P3: barrier-free i-loop. V hoisted to f32 regs (loop-invariant per lane).
//     H = relu(V + UpM) -> bf16; D = mfma(W2frag, Hfrag) gives row=q, col=j
//     so each lane owns 4 consecutive q -> two nontemporal dwordx4 stores.
// ---------------------------------------------------------------------------
__global__ __launch_bounds__(256) void fused_k(
    const int* __restrict__ ids, const float* __restrict__ emb,
    const float* __restrict__ W1, const float* __restrict__ b1,
    const float* __restrict__ W2, const float* __restrict__ b2,
    float* __restrict__ out, float* __restrict__ e_out)
{
  __shared__ int   ids_s[NO];
  __shared__ float psum[4][ND];
  __shared__ float mean_s[ND];
  __shared__ float M_s[ND];
  __shared__ float UpM_s[32 * 68];   // this block's 32 i-rows, padded
  __shared__ float V_s[NO * 68];     // all 64 j-rows, padded

  const int tid = threadIdx.x, blk = blockIdx.x;
  const int ic = blk & 1, b = (blk >> 1) & 127, l = blk >> 8;
  const int lane = tid & 63, wave = tid >> 6;
  const int qlo = lane & 15, g = lane >> 4;

  if (tid < NO) ids_s[tid] = ids[b * NO + tid];
  __syncthreads();

  // ---- P0: e gather + mean partials + exact e copy ----
  {
    const int d = lane;
    float s = 0.f;
#pragma unroll
    for (int nn = 0; nn < 16; ++nn) {
      const int n = wave * 16 + nn;
      const float v = emb[ids_s[n] * ND + d];
      if (l == 0 && (n >> 5) == ic) e_out[(b * NO + n) * ND + d] = v;
      s += v;
    }
    psum[wave][d] = s;
  }
  __syncthreads();
  if (tid < ND)
    mean_s[tid] = (psum[0][tid] + psum[1][tid] + psum[2][tid] + psum[3][tid]) * (1.0f / 64.0f);
  __syncthreads();

  // ---- P1: M_s[d] = mean . W1c[d] + b1 (f32) ----
  if (tid < ND) {
    const float* wrow = W1 + (l * ND + tid) * 192 + 128;
    float acc = 0.f;
#pragma unroll
    for (int c = 0; c < 16; ++c) {
      const f32x4 w = *(const f32x4*)(wrow + c * 4);
      const f32x4 m = *(const f32x4*)(&mean_s[c * 4]);
      acc += w[0] * m[0] + w[1] * m[1] + w[2] * m[2] + w[3] * m[3];
    }
    M_s[tid] = acc + b1[l * ND + tid];
  }
  __syncthreads();

  // ---- P2: first layer via MFMA. 24 tiles (8 U + 16 V), 6 per wave. ----
  // A-frag: lane&15 = output row (i or j pos), k-octet = g. From emb rows.
  // B-frag: lane&15 = d col, k-octet = g. From W1 rows (col 0..63 U, 64..127 V).
  // D: row = 4g+r, col = lane&15. U acc init = M_s[d] (fold mean+b1).
#pragma unroll
  for (int t6 = 0; t6 < 6; ++t6) {
    const int t = wave * 6 + t6;
    const bool isU = (t < 8);
    const int rt = isU ? (2 * ic + (t >> 2)) : ((t - 8) >> 2);  // global row-tile
    const int dt = t & 3;
    const int dcol = dt * 16 + qlo;
    const float* arow = emb + ids_s[rt * 16 + qlo] * ND;
    const float* brow = W1 + (l * ND + dcol) * 192 + (isU ? 0 : 64);
    const float minit = isU ? M_s[dcol] : 0.f;
    f32x4 acc = {minit, minit, minit, minit};
#pragma unroll
    for (int kh = 0; kh < 2; ++kh) {
      const int k0 = kh * 32 + g * 8;
      const bf16x8 af = pack_bf16(*(const f32x4*)(arow + k0), *(const f32x4*)(arow + k0 + 4));
      const bf16x8 bf = pack_bf16(*(const f32x4*)(brow + k0), *(const f32x4*)(brow + k0 + 4));
      acc = __builtin_amdgcn_mfma_f32_16x16x32_bf16(af, bf, acc, 0, 0, 0);
    }
    float* dst = isU ? &UpM_s[((t >> 2) * 16) * 68] : &V_s[(rt * 16) * 68];
#pragma unroll
    for (int r = 0; r < 4; ++r)
      dst[(4 * g + r) * 68 + dcol] = acc[r];
  }
  __syncthreads();

  // ---- P3 setup: hoist V (f32) + W2 frags + b2 into registers ----
  const int jA = wave * 16 + qlo;     // this lane's pair column j (fixed)
  f32x4 vf[2][2];
#pragma unroll
  for (int kt = 0; kt < 2; ++kt) {
    vf[kt][0] = *(const f32x4*)(&V_s[jA * 68 + kt * 32 + g * 8]);
    vf[kt][1] = *(const f32x4*)(&V_s[jA * 68 + kt * 32 + g * 8 + 4]);
  }
  bf16x8 wfrag[2][2];
#pragma unroll
  for (int qt = 0; qt < 2; ++qt)
#pragma unroll
    for (int kt = 0; kt < 2; ++kt) {
      const float* wp = W2 + (l * NQ + qt * 16 + qlo) * ND + kt * 32 + g * 8;
      wfrag[qt][kt] = pack_bf16(*(const f32x4*)wp, *(const f32x4*)(wp + 4));
    }
  const f32x4 b20 = *(const f32x4*)(b2 + l * NQ + g * 4);        // q = 4g+r
  const f32x4 b21 = *(const f32x4*)(b2 + l * NQ + 16 + g * 4);   // q = 16+4g+r

  const int i0 = ic * 32;
  float* outb = out + (size_t)(l * NB + b) * NP * NQ;

  // ---- P3: barrier-free i-loop ----
  for (int ii = 0; ii < 32; ++ii) {
    const float* upm = &UpM_s[ii * 68];
    bf16x8 hb[2];
#pragma unroll
    for (int kt = 0; kt < 2; ++kt) {
      const int k0 = kt * 32 + g * 8;
      const f32x4 r0 = *(const f32x4*)(upm + k0);
      const f32x4 r1 = *(const f32x4*)(upm + k0 + 4);
      f32x4 h0, h1;
#pragma unroll
      for (int e = 0; e < 4; ++e) {
        h0[e] = fmaxf(vf[kt][0][e] + r0[e], 0.0f);
        h1[e] = fmaxf(vf[kt][1][e] + r1[e], 0.0f);
      }
      hb[kt] = pack_bf16(h0, h1);
    }

    const f32x4 z = {0.f, 0.f, 0.f, 0.f};
    // Swapped operands: D[row=q][col=j]; lane holds q = 4g+r, j = qlo (+wave*16)
    f32x4 acc0 = __builtin_amdgcn_mfma_f32_16x16x32_bf16(wfrag[0][0], hb[0], z, 0, 0, 0);
    acc0 = __builtin_amdgcn_mfma_f32_16x16x32_bf16(wfrag[0][1], hb[1], acc0, 0, 0, 0);
    f32x4 acc1 = __builtin_amdgcn_mfma_f32_16x16x32_bf16(wfrag[1][0], hb[0], z, 0, 0, 0);
    acc1 = __builtin_amdgcn_mfma_f32_16x16x32_bf16(wfrag[1][1], hb[1], acc1, 0, 0, 0);

    const int i = i0 + ii;
    if (jA != i) {
      const int p = (jA < i) ? jA : jA - 1;
      float* base = outb + ((size_t)i * 63 + p) * NQ + g * 4;
      f32x4 o0, o1;
#pragma unroll
      for (int r = 0; r < 4; ++r) {
        o0[r] = sigm(acc0[r] + b20[r]);
        o1[r] = sigm(acc1[r] + b21[r]);
      }
      __builtin_nontemporal_store(o0, (f32x4*)base);
      __builtin_nontemporal_store(o1, (f32x4*)(base + 16));
    }
  }
}

// ---------------------------------------------------------------------------
extern "C" void kernel_launch(void* const* d_in, const int* in_sizes, int n_in,
                              void* d_out, int out_size, void* d_ws, size_t ws_size,
                              hipStream_t stream) {
  const int*   ids = (const int*)d_in[0];
  const float* emb = (const float*)d_in[1];
  const float* W1  = (const float*)d_in[2];
  const float* b1  = (const float*)d_in[3];
  const float* W2  = (const float*)d_in[4];
  const float* b2  = (const float*)d_in[5];
  float* out = (float*)d_out;
  float* e_out = out + (size_t)NL * NB * NP * NQ;  // e appended after preds

  fused_k<<<NL * NB * 2, 256, 0, stream>>>(ids, emb, W1, b1, W2, b2, out, e_out);
}

// Round 3
// 54.772 us; speedup vs baseline: 1.4832x; 1.4832x over previous
//
#include <hip/hip_runtime.h>
#include <hip/hip_bf16.h>

// Sizes (fixed by the reference)
#define NL 3      // layers
#define NB 128    // batch
#define NO 64     // objects
#define ND 64     // emb dim
#define NQ 32     // preds per pair
#define NP 4032   // 64*63 ordered pairs

typedef __bf16 bf16x8 __attribute__((ext_vector_type(8)));
typedef float  f32x4  __attribute__((ext_vector_type(4)));

__device__ __forceinline__ float sigm(float x) {
  return __builtin_amdgcn_rcpf(1.0f + __expf(-x));
}

__device__ __forceinline__ bf16x8 pack_bf16(const f32x4 a, const f32x4 b) {
  bf16x8 r;
  r[0] = (__bf16)a[0]; r[1] = (__bf16)a[1]; r[2] = (__bf16)a[2]; r[3] = (__bf16)a[3];
  r[4] = (__bf16)b[0]; r[5] = (__bf16)b[1]; r[6] = (__bf16)b[2]; r[7] = (__bf16)b[3];
  return r;
}

// ---------------------------------------------------------------------------
// Single fused kernel. grid = 3*128*2 = 768 (blk = l*256 + b*2 + ic), 256 thr.
// Identical to round-2 EXCEPT: plain f32x4 stores instead of nontemporal
// (isolating the nt-store regression hypothesis).
// ---------------------------------------------------------------------------
__global__ __launch_bounds__(256) void fused_k(
    const int* __restrict__ ids, const float* __restrict__ emb,
    const float* __restrict__ W1, const float* __restrict__ b1,
    const float* __restrict__ W2, const float* __restrict__ b2,
    float* __restrict__ out, float* __restrict__ e_out)
{
  __shared__ int   ids_s[NO];
  __shared__ float psum[4][ND];
  __shared__ float mean_s[ND];
  __shared__ float M_s[ND];
  __shared__ float UpM_s[32 * 68];   // this block's 32 i-rows, padded
  __shared__ float V_s[NO * 68];     // all 64 j-rows, padded

  const int tid = threadIdx.x, blk = blockIdx.x;
  const int ic = blk & 1, b = (blk >> 1) & 127, l = blk >> 8;
  const int lane = tid & 63, wave = tid >> 6;
  const int qlo = lane & 15, g = lane >> 4;

  if (tid < NO) ids_s[tid] = ids[b * NO + tid];
  __syncthreads();

  // ---- P0: e gather + mean partials + exact e copy ----
  {
    const int d = lane;
    float s = 0.f;
#pragma unroll
    for (int nn = 0; nn < 16; ++nn) {
      const int n = wave * 16 + nn;
      const float v = emb[ids_s[n] * ND + d];
      if (l == 0 && (n >> 5) == ic) e_out[(b * NO + n) * ND + d] = v;
      s += v;
    }
    psum[wave][d] = s;
  }
  __syncthreads();
  if (tid < ND)
    mean_s[tid] = (psum[0][tid] + psum[1][tid] + psum[2][tid] + psum[3][tid]) * (1.0f / 64.0f);
  __syncthreads();

  // ---- P1: M_s[d] = mean . W1c[d] + b1 (f32) ----
  if (tid < ND) {
    const float* wrow = W1 + (l * ND + tid) * 192 + 128;
    float acc = 0.f;
#pragma unroll
    for (int c = 0; c < 16; ++c) {
      const f32x4 w = *(const f32x4*)(wrow + c * 4);
      const f32x4 m = *(const f32x4*)(&mean_s[c * 4]);
      acc += w[0] * m[0] + w[1] * m[1] + w[2] * m[2] + w[3] * m[3];
    }
    M_s[tid] = acc + b1[l * ND + tid];
  }
  __syncthreads();

  // ---- P2: first layer via MFMA. 24 tiles (8 U + 16 V), 6 per wave. ----
#pragma unroll
  for (int t6 = 0; t6 < 6; ++t6) {
    const int t = wave * 6 + t6;
    const bool isU = (t < 8);
    const int rt = isU ? (2 * ic + (t >> 2)) : ((t - 8) >> 2);  // global row-tile
    const int dt = t & 3;
    const int dcol = dt * 16 + qlo;
    const float* arow = emb + ids_s[rt * 16 + qlo] * ND;
    const float* brow = W1 + (l * ND + dcol) * 192 + (isU ? 0 : 64);
    const float minit = isU ? M_s[dcol] : 0.f;
    f32x4 acc = {minit, minit, minit, minit};
#pragma unroll
    for (int kh = 0; kh < 2; ++kh) {
      const int k0 = kh * 32 + g * 8;
      const bf16x8 af = pack_bf16(*(const f32x4*)(arow + k0), *(const f32x4*)(arow + k0 + 4));
      const bf16x8 bf = pack_bf16(*(const f32x4*)(brow + k0), *(const f32x4*)(brow + k0 + 4));
      acc = __builtin_amdgcn_mfma_f32_16x16x32_bf16(af, bf, acc, 0, 0, 0);
    }
    float* dst = isU ? &UpM_s[((t >> 2) * 16) * 68] : &V_s[(rt * 16) * 68];
#pragma unroll
    for (int r = 0; r < 4; ++r)
      dst[(4 * g + r) * 68 + dcol] = acc[r];
  }
  __syncthreads();

  // ---- P3 setup: hoist V (f32) + W2 frags + b2 into registers ----
  const int jA = wave * 16 + qlo;     // this lane's pair column j (fixed)
  f32x4 vf[2][2];
#pragma unroll
  for (int kt = 0; kt < 2; ++kt) {
    vf[kt][0] = *(const f32x4*)(&V_s[jA * 68 + kt * 32 + g * 8]);
    vf[kt][1] = *(const f32x4*)(&V_s[jA * 68 + kt * 32 + g * 8 + 4]);
  }
  bf16x8 wfrag[2][2];
#pragma unroll
  for (int qt = 0; qt < 2; ++qt)
#pragma unroll
    for (int kt = 0; kt < 2; ++kt) {
      const float* wp = W2 + (l * NQ + qt * 16 + qlo) * ND + kt * 32 + g * 8;
      wfrag[qt][kt] = pack_bf16(*(const f32x4*)wp, *(const f32x4*)(wp + 4));
    }
  const f32x4 b20 = *(const f32x4*)(b2 + l * NQ + g * 4);        // q = 4g+r
  const f32x4 b21 = *(const f32x4*)(b2 + l * NQ + 16 + g * 4);   // q = 16+4g+r

  const int i0 = ic * 32;
  float* outb = out + (size_t)(l * NB + b) * NP * NQ;

  // ---- P3: barrier-free i-loop ----
  for (int ii = 0; ii < 32; ++ii) {
    const float* upm = &UpM_s[ii * 68];
    bf16x8 hb[2];
#pragma unroll
    for (int kt = 0; kt < 2; ++kt) {
      const int k0 = kt * 32 + g * 8;
      const f32x4 r0 = *(const f32x4*)(upm + k0);
      const f32x4 r1 = *(const f32x4*)(upm + k0 + 4);
      f32x4 h0, h1;
#pragma unroll
      for (int e = 0; e < 4; ++e) {
        h0[e] = fmaxf(vf[kt][0][e] + r0[e], 0.0f);
        h1[e] = fmaxf(vf[kt][1][e] + r1[e], 0.0f);
      }
      hb[kt] = pack_bf16(h0, h1);
    }

    const f32x4 z = {0.f, 0.f, 0.f, 0.f};
    // Swapped operands: D[row=q][col=j]; lane holds q = 4g+r, j = qlo (+wave*16)
    f32x4 acc0 = __builtin_amdgcn_mfma_f32_16x16x32_bf16(wfrag[0][0], hb[0], z, 0, 0, 0);
    acc0 = __builtin_amdgcn_mfma_f32_16x16x32_bf16(wfrag[0][1], hb[1], acc0, 0, 0, 0);
    f32x4 acc1 = __builtin_amdgcn_mfma_f32_16x16x32_bf16(wfrag[1][0], hb[0], z, 0, 0, 0);
    acc1 = __builtin_amdgcn_mfma_f32_16x16x32_bf16(wfrag[1][1], hb[1], acc1, 0, 0, 0);

    const int i = i0 + ii;
    if (jA != i) {
      const int p = (jA < i) ? jA : jA - 1;
      float* base = outb + ((size_t)i * 63 + p) * NQ + g * 4;
      f32x4 o0, o1;
#pragma unroll
      for (int r = 0; r < 4; ++r) {
        o0[r] = sigm(acc0[r] + b20[r]);
        o1[r] = sigm(acc1[r] + b21[r]);
      }
      *(f32x4*)base = o0;           // plain stores: L2 write-combine
      *(f32x4*)(base + 16) = o1;
    }
  }
}

// ---------------------------------------------------------------------------
extern "C" void kernel_launch(void* const* d_in, const int* in_sizes, int n_in,
                              void* d_out, int out_size, void* d_ws, size_t ws_size,
                              hipStream_t stream) {
  const int*   ids = (const int*)d_in[0];
  const float* emb = (const float*)d_in[1];
  const float* W1  = (const float*)d_in[2];
  const float* b1  = (const float*)d_in[3];
  const float* W2  = (const float*)d_in[4];
  const float* b2  = (const float*)d_in[5];
  float* out = (float*)d_out;
  float* e_out = out + (size_t)NL * NB * NP * NQ;  // e appended after preds

  fused_k<<<NL * NB * 2, 256, 0, stream>>>(ids, emb, W1, b1, W2, b2, out, e_out);
}

// Round 4
// 46.411 us; speedup vs baseline: 1.7504x; 1.1802x over previous
//
#include <hip/hip_runtime.h>
#include <hip/hip_bf16.h>

// Sizes (fixed by the reference)
#define NL 3      // layers
#define NB 128    // batch
#define NO 64     // objects
#define ND 64     // emb dim
#define NQ 32     // preds per pair
#define NP 4032   // 64*63 ordered pairs

typedef __bf16 bf16x8 __attribute__((ext_vector_type(8)));
typedef float  f32x4  __attribute__((ext_vector_type(4)));

__device__ __forceinline__ float sigm(float x) {
  return __builtin_amdgcn_rcpf(1.0f + __expf(-x));
}

__device__ __forceinline__ bf16x8 pack_bf16(const f32x4 a, const f32x4 b) {
  bf16x8 r;
  r[0] = (__bf16)a[0]; r[1] = (__bf16)a[1]; r[2] = (__bf16)a[2]; r[3] = (__bf16)a[3];
  r[4] = (__bf16)b[0]; r[5] = (__bf16)b[1]; r[6] = (__bf16)b[2]; r[7] = (__bf16)b[3];
  return r;
}

// ---------------------------------------------------------------------------
// Kernel 1: precompute (verbatim from round 1 — known good)
//   blocks 0..127   : b -> mean, M[l][b][d] = mean.W1c + b1 ; exact e copy
//   blocks 128..133 : (l,half) -> Ut / Vt tables via vector FMA
// ---------------------------------------------------------------------------
__global__ __launch_bounds__(256) void precomp_k(
    const int* __restrict__ ids, const float* __restrict__ emb,
    const float* __restrict__ W1, const float* __restrict__ b1,
    float* __restrict__ Ut, float* __restrict__ Vt, float* __restrict__ M,
    float* __restrict__ e_out)
{
  const int blk = blockIdx.x, tid = threadIdx.x;

  if (blk < NB) {
    __shared__ int   ids_s[NO];
    __shared__ float psum[4][ND];
    __shared__ float mean_s[ND];
    const int b = blk;
    if (tid < NO) ids_s[tid] = ids[b * NO + tid];
    __syncthreads();

    {
      const int d = tid & 63, ng = tid >> 6;
      float s = 0.f;
#pragma unroll
      for (int nn = 0; nn < 16; ++nn) {
        const int n = ng * 16 + nn;
        const float v = emb[ids_s[n] * ND + d];
        e_out[(b * NO + n) * ND + d] = v;   // exact f32 copy of e
        s += v;
      }
      psum[ng][d] = s;
    }
    __syncthreads();
    if (tid < ND)
      mean_s[tid] = (psum[0][tid] + psum[1][tid] + psum[2][tid] + psum[3][tid]) * (1.0f / 64.0f);
    __syncthreads();

    if (tid < 192) {
      const int l = tid >> 6, d = tid & 63;
      const float* wrow = W1 + (l * ND + d) * 192 + 128;
      float acc = 0.f;
#pragma unroll
      for (int c4 = 0; c4 < 16; ++c4) {
        const f32x4 w = *(const f32x4*)(wrow + c4 * 4);
        const f32x4 m = *(const f32x4*)(&mean_s[c4 * 4]);
        acc += w[0] * m[0] + w[1] * m[1] + w[2] * m[2] + w[3] * m[3];
      }
      M[(l * NB + b) * ND + d] = acc + b1[l * ND + d];
    }
  } else {
    const int idx = blk - NB;
    const int l = idx >> 1, half = idx & 1;
    __shared__ float e_s[NO][68];
    {
      const int o = tid >> 2, c0 = (tid & 3) * 16;
      const float* er = emb + o * ND + c0;
#pragma unroll
      for (int c = 0; c < 16; c += 4)
        *(f32x4*)(&e_s[o][c0 + c]) = *(const f32x4*)(er + c);
    }
    __syncthreads();

    const int d = tid & 63, og = tid >> 6;   // each thread: 16 objects x 1 d
    const float* wrow = W1 + (l * ND + d) * 192 + half * 64;
    float acc[16];
#pragma unroll
    for (int k = 0; k < 16; ++k) acc[k] = 0.f;
#pragma unroll
    for (int c4 = 0; c4 < 16; ++c4) {
      const f32x4 w = *(const f32x4*)(wrow + c4 * 4);
#pragma unroll
      for (int oo = 0; oo < 16; ++oo) {
        const f32x4 e = *(const f32x4*)(&e_s[og * 16 + oo][c4 * 4]);  // broadcast
        acc[oo] += e[0] * w[0] + e[1] * w[1] + e[2] * w[2] + e[3] * w[3];
      }
    }
    float* T = half ? Vt : Ut;
#pragma unroll
    for (int oo = 0; oo < 16; ++oo)
      T[(l * NO + og * 16 + oo) * ND + d] = acc[oo];
  }
}

// ---------------------------------------------------------------------------
// Kernel 2: lean main. grid = 768 (blk = l*256 + b*2 + ic), 256 threads.
// Prologue: UpM (32 rows) -> LDS from Ut/M; V/W2/b2 -> regs. ONE syncthreads.
// i-loop: H=relu(V+UpM)->bf16, D=mfma(W2,H) (row=q,col=j), sigmoid,
// two plain dwordx4 stores per lane-iter.
// ---------------------------------------------------------------------------
__global__ __launch_bounds__(256) void main_k(
    const int* __restrict__ ids, const float* __restrict__ W2,
    const float* __restrict__ b2,
    const float* __restrict__ Ut, const float* __restrict__ Vt,
    const float* __restrict__ M, float* __restrict__ out)
{
  __shared__ float UpM_s[32 * 68];

  const int tid = threadIdx.x, blk = blockIdx.x;
  const int ic = blk & 1, b = (blk >> 1) & 127, l = blk >> 8;
  const int lane = tid & 63, wave = tid >> 6;
  const int qlo = lane & 15, g = lane >> 4;
  const int i0 = ic * 32;

  // ---- stage UpM: 32 rows x 64 cols, 8 floats/thread ----
  {
    const int row = tid >> 3, c0 = (tid & 7) * 8;
    const int idi = ids[b * NO + i0 + row];
    const float* u = Ut + (l * NO + idi) * ND + c0;
    const float* m = M + (l * NB + b) * ND + c0;
    const f32x4 a0 = *(const f32x4*)u + *(const f32x4*)m;
    const f32x4 a1 = *(const f32x4*)(u + 4) + *(const f32x4*)(m + 4);
    *(f32x4*)(&UpM_s[row * 68 + c0]) = a0;
    *(f32x4*)(&UpM_s[row * 68 + c0 + 4]) = a1;
  }

  // ---- V (f32), W2 frags, b2 into registers (loop-invariant) ----
  const int jA = wave * 16 + qlo;        // this lane's pair column j (fixed)
  const int idj = ids[b * NO + jA];
  const float* vrow = Vt + (l * NO + idj) * ND;
  f32x4 vf[2][2];
#pragma unroll
  for (int kt = 0; kt < 2; ++kt) {
    vf[kt][0] = *(const f32x4*)(vrow + kt * 32 + g * 8);
    vf[kt][1] = *(const f32x4*)(vrow + kt * 32 + g * 8 + 4);
  }
  bf16x8 wfrag[2][2];
#pragma unroll
  for (int qt = 0; qt < 2; ++qt)
#pragma unroll
    for (int kt = 0; kt < 2; ++kt) {
      const float* wp = W2 + (l * NQ + qt * 16 + qlo) * ND + kt * 32 + g * 8;
      wfrag[qt][kt] = pack_bf16(*(const f32x4*)wp, *(const f32x4*)(wp + 4));
    }
  const f32x4 b20 = *(const f32x4*)(b2 + l * NQ + g * 4);        // q = 4g+r
  const f32x4 b21 = *(const f32x4*)(b2 + l * NQ + 16 + g * 4);   // q = 16+4g+r

  __syncthreads();

  float* outb = out + (size_t)(l * NB + b) * NP * NQ;

  // ---- barrier-free i-loop ----
  for (int ii = 0; ii < 32; ++ii) {
    const float* upm = &UpM_s[ii * 68];
    bf16x8 hb[2];
#pragma unroll
    for (int kt = 0; kt < 2; ++kt) {
      const int k0 = kt * 32 + g * 8;
      const f32x4 r0 = *(const f32x4*)(upm + k0);
      const f32x4 r1 = *(const f32x4*)(upm + k0 + 4);
      f32x4 h0, h1;
#pragma unroll
      for (int e = 0; e < 4; ++e) {
        h0[e] = fmaxf(vf[kt][0][e] + r0[e], 0.0f);
        h1[e] = fmaxf(vf[kt][1][e] + r1[e], 0.0f);
      }
      hb[kt] = pack_bf16(h0, h1);
    }

    const f32x4 z = {0.f, 0.f, 0.f, 0.f};
    // Swapped operands: D[row=q][col=j]; lane holds q = 4g+r, j = qlo+wave*16
    f32x4 acc0 = __builtin_amdgcn_mfma_f32_16x16x32_bf16(wfrag[0][0], hb[0], z, 0, 0, 0);
    acc0 = __builtin_amdgcn_mfma_f32_16x16x32_bf16(wfrag[0][1], hb[1], acc0, 0, 0, 0);
    f32x4 acc1 = __builtin_amdgcn_mfma_f32_16x16x32_bf16(wfrag[1][0], hb[0], z, 0, 0, 0);
    acc1 = __builtin_amdgcn_mfma_f32_16x16x32_bf16(wfrag[1][1], hb[1], acc1, 0, 0, 0);

    const int i = i0 + ii;
    if (jA != i) {
      const int p = (jA < i) ? jA : jA - 1;
      float* base = outb + ((size_t)i * 63 + p) * NQ + g * 4;
      f32x4 o0, o1;
#pragma unroll
      for (int r = 0; r < 4; ++r) {
        o0[r] = sigm(acc0[r] + b20[r]);
        o1[r] = sigm(acc1[r] + b21[r]);
      }
      *(f32x4*)base = o0;
      *(f32x4*)(base + 16) = o1;
    }
  }
}

// ---------------------------------------------------------------------------
extern "C" void kernel_launch(void* const* d_in, const int* in_sizes, int n_in,
                              void* d_out, int out_size, void* d_ws, size_t ws_size,
                              hipStream_t stream) {
  const int*   ids = (const int*)d_in[0];
  const float* emb = (const float*)d_in[1];
  const float* W1  = (const float*)d_in[2];
  const float* b1  = (const float*)d_in[3];
  const float* W2  = (const float*)d_in[4];
  const float* b2  = (const float*)d_in[5];
  float* out = (float*)d_out;

  float* Ut = (float*)d_ws;              // [3][64][64] f32
  float* Vt = Ut + NL * NO * ND;         // [3][64][64] f32
  float* M  = Vt + NL * NO * ND;         // [3][128][64] f32  (192 KB of ws)
  float* e_out = out + (size_t)NL * NB * NP * NQ;  // e appended after preds

  precomp_k<<<NB + 2 * NL, 256, 0, stream>>>(ids, emb, W1, b1, Ut, Vt, M, e_out);
  main_k<<<NL * NB * 2, 256, 0, stream>>>(ids, W2, b2, Ut, Vt, M, out);
}

// Round 5
// 45.040 us; speedup vs baseline: 1.8036x; 1.0304x over previous
//
#include <hip/hip_runtime.h>
#include <hip/hip_bf16.h>

// Sizes (fixed by the reference)
#define NL 3      // layers
#define NB 128    // batch
#define NO 64     // objects
#define ND 64     // emb dim
#define NQ 32     // preds per pair
#define NP 4032   // 64*63 ordered pairs

typedef __bf16 bf16x8 __attribute__((ext_vector_type(8)));
typedef float  f32x4  __attribute__((ext_vector_type(4)));

__device__ __forceinline__ float sigm(float x) {
  return __builtin_amdgcn_rcpf(1.0f + __expf(-x));
}

__device__ __forceinline__ bf16x8 pack_bf16(const f32x4 a, const f32x4 b) {
  bf16x8 r;
  r[0] = (__bf16)a[0]; r[1] = (__bf16)a[1]; r[2] = (__bf16)a[2]; r[3] = (__bf16)a[3];
  r[4] = (__bf16)b[0]; r[5] = (__bf16)b[1]; r[6] = (__bf16)b[2]; r[7] = (__bf16)b[3];
  return r;
}

// ---------------------------------------------------------------------------
// Kernel 1: precompute (verbatim from round 1 — known good)
//   blocks 0..127   : b -> mean, M[l][b][d] = mean.W1c + b1 ; exact e copy
//   blocks 128..133 : (l,half) -> Ut / Vt tables via vector FMA
// ---------------------------------------------------------------------------
__global__ __launch_bounds__(256) void precomp_k(
    const int* __restrict__ ids, const float* __restrict__ emb,
    const float* __restrict__ W1, const float* __restrict__ b1,
    float* __restrict__ Ut, float* __restrict__ Vt, float* __restrict__ M,
    float* __restrict__ e_out)
{
  const int blk = blockIdx.x, tid = threadIdx.x;

  if (blk < NB) {
    __shared__ int   ids_s[NO];
    __shared__ float psum[4][ND];
    __shared__ float mean_s[ND];
    const int b = blk;
    if (tid < NO) ids_s[tid] = ids[b * NO + tid];
    __syncthreads();

    {
      const int d = tid & 63, ng = tid >> 6;
      float s = 0.f;
#pragma unroll
      for (int nn = 0; nn < 16; ++nn) {
        const int n = ng * 16 + nn;
        const float v = emb[ids_s[n] * ND + d];
        e_out[(b * NO + n) * ND + d] = v;   // exact f32 copy of e
        s += v;
      }
      psum[ng][d] = s;
    }
    __syncthreads();
    if (tid < ND)
      mean_s[tid] = (psum[0][tid] + psum[1][tid] + psum[2][tid] + psum[3][tid]) * (1.0f / 64.0f);
    __syncthreads();

    if (tid < 192) {
      const int l = tid >> 6, d = tid & 63;
      const float* wrow = W1 + (l * ND + d) * 192 + 128;
      float acc = 0.f;
#pragma unroll
      for (int c4 = 0; c4 < 16; ++c4) {
        const f32x4 w = *(const f32x4*)(wrow + c4 * 4);
        const f32x4 m = *(const f32x4*)(&mean_s[c4 * 4]);
        acc += w[0] * m[0] + w[1] * m[1] + w[2] * m[2] + w[3] * m[3];
      }
      M[(l * NB + b) * ND + d] = acc + b1[l * ND + d];
    }
  } else {
    const int idx = blk - NB;
    const int l = idx >> 1, half = idx & 1;
    __shared__ float e_s[NO][68];
    {
      const int o = tid >> 2, c0 = (tid & 3) * 16;
      const float* er = emb + o * ND + c0;
#pragma unroll
      for (int c = 0; c < 16; c += 4)
        *(f32x4*)(&e_s[o][c0 + c]) = *(const f32x4*)(er + c);
    }
    __syncthreads();

    const int d = tid & 63, og = tid >> 6;   // each thread: 16 objects x 1 d
    const float* wrow = W1 + (l * ND + d) * 192 + half * 64;
    float acc[16];
#pragma unroll
    for (int k = 0; k < 16; ++k) acc[k] = 0.f;
#pragma unroll
    for (int c4 = 0; c4 < 16; ++c4) {
      const f32x4 w = *(const f32x4*)(wrow + c4 * 4);
#pragma unroll
      for (int oo = 0; oo < 16; ++oo) {
        const f32x4 e = *(const f32x4*)(&e_s[og * 16 + oo][c4 * 4]);  // broadcast
        acc[oo] += e[0] * w[0] + e[1] * w[1] + e[2] * w[2] + e[3] * w[3];
      }
    }
    float* T = half ? Vt : Ut;
#pragma unroll
    for (int oo = 0; oo < 16; ++oo)
      T[(l * NO + og * 16 + oo) * ND + d] = acc[oo];
  }
}

// ---------------------------------------------------------------------------
// Kernel 2: lean main. grid = 3*128*4 = 1536 (blk = l*512 + b*4 + ic), 256 thr.
// 16 i-rows per block -> 6 blocks/CU = 24 waves/CU (R4 had 12). Unroll 2 for
// cross-iteration ILP. Otherwise identical to round 4.
// ---------------------------------------------------------------------------
__global__ __launch_bounds__(256, 6) void main_k(
    const int* __restrict__ ids, const float* __restrict__ W2,
    const float* __restrict__ b2,
    const float* __restrict__ Ut, const float* __restrict__ Vt,
    const float* __restrict__ M, float* __restrict__ out)
{
  __shared__ float UpM_s[16 * 68];

  const int tid = threadIdx.x, blk = blockIdx.x;
  const int ic = blk & 3, b = (blk >> 2) & 127, l = blk >> 9;
  const int lane = tid & 63, wave = tid >> 6;
  const int qlo = lane & 15, g = lane >> 4;
  const int i0 = ic * 16;

  // ---- stage UpM: 16 rows x 64 cols, one f32x4 per thread ----
  {
    const int row = tid >> 4, c0 = (tid & 15) * 4;
    const int idi = ids[b * NO + i0 + row];
    const float* u = Ut + (l * NO + idi) * ND + c0;
    const float* m = M + (l * NB + b) * ND + c0;
    *(f32x4*)(&UpM_s[row * 68 + c0]) = *(const f32x4*)u + *(const f32x4*)m;
  }

  // ---- V (f32), W2 frags, b2 into registers (loop-invariant) ----
  const int jA = wave * 16 + qlo;        // this lane's pair column j (fixed)
  const int idj = ids[b * NO + jA];
  const float* vrow = Vt + (l * NO + idj) * ND;
  f32x4 vf[2][2];
#pragma unroll
  for (int kt = 0; kt < 2; ++kt) {
    vf[kt][0] = *(const f32x4*)(vrow + kt * 32 + g * 8);
    vf[kt][1] = *(const f32x4*)(vrow + kt * 32 + g * 8 + 4);
  }
  bf16x8 wfrag[2][2];
#pragma unroll
  for (int qt = 0; qt < 2; ++qt)
#pragma unroll
    for (int kt = 0; kt < 2; ++kt) {
      const float* wp = W2 + (l * NQ + qt * 16 + qlo) * ND + kt * 32 + g * 8;
      wfrag[qt][kt] = pack_bf16(*(const f32x4*)wp, *(const f32x4*)(wp + 4));
    }
  const f32x4 b20 = *(const f32x4*)(b2 + l * NQ + g * 4);        // q = 4g+r
  const f32x4 b21 = *(const f32x4*)(b2 + l * NQ + 16 + g * 4);   // q = 16+4g+r

  __syncthreads();

  float* outb = out + (size_t)(l * NB + b) * NP * NQ;

  // ---- barrier-free i-loop (unroll 2 for cross-iter ILP) ----
#pragma unroll 2
  for (int ii = 0; ii < 16; ++ii) {
    const float* upm = &UpM_s[ii * 68];
    bf16x8 hb[2];
#pragma unroll
    for (int kt = 0; kt < 2; ++kt) {
      const int k0 = kt * 32 + g * 8;
      const f32x4 r0 = *(const f32x4*)(upm + k0);
      const f32x4 r1 = *(const f32x4*)(upm + k0 + 4);
      f32x4 h0, h1;
#pragma unroll
      for (int e = 0; e < 4; ++e) {
        h0[e] = fmaxf(vf[kt][0][e] + r0[e], 0.0f);
        h1[e] = fmaxf(vf[kt][1][e] + r1[e], 0.0f);
      }
      hb[kt] = pack_bf16(h0, h1);
    }

    const f32x4 z = {0.f, 0.f, 0.f, 0.f};
    // Swapped operands: D[row=q][col=j]; lane holds q = 4g+r, j = qlo+wave*16
    f32x4 acc0 = __builtin_amdgcn_mfma_f32_16x16x32_bf16(wfrag[0][0], hb[0], z, 0, 0, 0);
    acc0 = __builtin_amdgcn_mfma_f32_16x16x32_bf16(wfrag[0][1], hb[1], acc0, 0, 0, 0);
    f32x4 acc1 = __builtin_amdgcn_mfma_f32_16x16x32_bf16(wfrag[1][0], hb[0], z, 0, 0, 0);
    acc1 = __builtin_amdgcn_mfma_f32_16x16x32_bf16(wfrag[1][1], hb[1], acc1, 0, 0, 0);

    const int i = i0 + ii;
    if (jA != i) {
      const int p = (jA < i) ? jA : jA - 1;
      float* base = outb + ((size_t)i * 63 + p) * NQ + g * 4;
      f32x4 o0, o1;
#pragma unroll
      for (int r = 0; r < 4; ++r) {
        o0[r] = sigm(acc0[r] + b20[r]);
        o1[r] = sigm(acc1[r] + b21[r]);
      }
      *(f32x4*)base = o0;
      *(f32x4*)(base + 16) = o1;
    }
  }
}

// ---------------------------------------------------------------------------
extern "C" void kernel_launch(void* const* d_in, const int* in_sizes, int n_in,
                              void* d_out, int out_size, void* d_ws, size_t ws_size,
                              hipStream_t stream) {
  const int*   ids = (const int*)d_in[0];
  const float* emb = (const float*)d_in[1];
  const float* W1  = (const float*)d_in[2];
  const float* b1  = (const float*)d_in[3];
  const float* W2  = (const float*)d_in[4];
  const float* b2  = (const float*)d_in[5];
  float* out = (float*)d_out;

  float* Ut = (float*)d_ws;              // [3][64][64] f32
  float* Vt = Ut + NL * NO * ND;         // [3][64][64] f32
  float* M  = Vt + NL * NO * ND;         // [3][128][64] f32  (192 KB of ws)
  float* e_out = out + (size_t)NL * NB * NP * NQ;  // e appended after preds

  precomp_k<<<NB + 2 * NL, 256, 0, stream>>>(ids, emb, W1, b1, Ut, Vt, M, e_out);
  main_k<<<NL * NB * 4, 256, 0, stream>>>(ids, W2, b2, Ut, Vt, M, out);
}